// Round 11
// baseline (146.214 us; speedup 1.0000x reference)
//
#include <hip/hip_runtime.h>
#include <hip/hip_bf16.h>

// CfC / liquid-RNN scan on MFMA, R17 = R16 + LDS b64-packing + conflict fix
// + parallel hi/lo accumulator chains.
// R16 post-mortem: 59.4us, absmax 0.0103 -- issue-diet law confirmed 3rd
// time. R17 continues the diet:
//  (1) b64-packed exchange buffers: hbuf[2][64][2], abuf[4][64][2],
//      xbuf[4][18][2] -- LDS ops/step/wave 20 -> 11 (reads 16->8, writes
//      4->3), plus addr-calc savings. Same transposed idiom (2-way free).
//  (2) xbuf row stride 18 dwords: kills the 1.08M bank conflicts (was 4
//      lanes/bank with 2 addrs at stride 16).
//  (3) phase1/phase2 hi+lo as TWO parallel MFMA accumulators + 4-wide add:
//      removes one MFMA dep-latency from the recurrent chain per phase.
//      Reassociation-only change (~ulp).
// Everything else identical to R16 (head hi-only, bias C-in, setprio,
// 2 non-draining barriers, vmcnt never drained).

#define CIN      16
#define UNITS    32
#define BACKBONE 64
#define CZ       48
#define TSTEPS   32
#define HW       4096
#define NPIX     16
#define NTHREADS 256

typedef __attribute__((ext_vector_type(8))) short  short8;
typedef __attribute__((ext_vector_type(8))) __bf16 bf16x8;
typedef __attribute__((ext_vector_type(4))) float  float4v;
typedef __attribute__((ext_vector_type(4))) unsigned int uint4v;
typedef __attribute__((ext_vector_type(2))) unsigned int uint2v;

// LDS-only barrier: drain LDS pipe, sync waves; vmem stays in flight.
#define BAR_LDS() asm volatile("s_waitcnt lgkmcnt(0)\n\ts_barrier" ::: "memory")

__device__ __forceinline__ unsigned short bf16_rne(float f) {
    unsigned u = __float_as_uint(f);
    return (unsigned short)((u + 0x7FFFu + ((u >> 16) & 1u)) >> 16);
}
__device__ __forceinline__ float bf16_tof(unsigned short h) {
    return __uint_as_float(((unsigned)h) << 16);
}
// packed f32x2 -> bf16x2 (RNE), single VALU op
__device__ __forceinline__ unsigned cvt_pk_bf16(float lo, float hi) {
    unsigned r;
    asm("v_cvt_pk_bf16_f32 %0, %1, %2" : "=v"(r) : "v"(lo), "v"(hi));
    return r;
}

#if __has_builtin(__builtin_amdgcn_exp2f)
#define EXP2F(x) __builtin_amdgcn_exp2f(x)
#else
#define EXP2F(x) __expf(0.69314718056f * (x))
#endif
#if __has_builtin(__builtin_amdgcn_rcpf)
#define RCPF(x) __builtin_amdgcn_rcpf(x)
#else
#define RCPF(x) __fdividef(1.0f, (x))
#endif

// 1.7159*tanh(0.666*v) = 1.7159 - 3.4318/(2^(1.332*log2e*v)+1)
__device__ __forceinline__ float lecun_tanh_f(float v) {
    float e = EXP2F(1.92166925f * v);
    return fmaf(-3.4318f, RCPF(e + 1.0f), 1.7159f);
}
__device__ __forceinline__ float tanh_f(float v) {
    float e = EXP2F(2.88539008f * v);
    return fmaf(-2.0f, RCPF(e + 1.0f), 1.0f);
}
__device__ __forceinline__ float sigmoid_f(float v) {
    float e = EXP2F(-1.44269504f * v);
    return RCPF(1.0f + e);
}
__device__ __forceinline__ float4v mfma16(bf16x8 a, bf16x8 b, float4v c) {
    return __builtin_amdgcn_mfma_f32_16x16x32_bf16(a, b, c, 0, 0, 0);
}
__device__ __forceinline__ void split8(const float* v, bf16x8& hi, bf16x8& lo) {
    short8 sh, sl;
    #pragma unroll
    for (int j = 0; j < 8; ++j) {
        unsigned short h = bf16_rne(v[j]);
        sh[j] = (short)h;
        sl[j] = (short)bf16_rne(v[j] - bf16_tof(h));
    }
    hi = __builtin_bit_cast(bf16x8, sh);
    lo = __builtin_bit_cast(bf16x8, sl);
}
__device__ __forceinline__ bf16x8 pack8hi(const float* v) {
    short8 sh;
    #pragma unroll
    for (int j = 0; j < 8; ++j) sh[j] = (short)bf16_rne(v[j]);
    return __builtin_bit_cast(bf16x8, sh);
}

__global__ __launch_bounds__(NTHREADS, 4)
void cfc_mfma_kernel(const float* __restrict__ x,   const float* __restrict__ Wb,
                     const float* __restrict__ bb,
                     const float* __restrict__ Wff1, const float* __restrict__ bff1,
                     const float* __restrict__ Wff2, const float* __restrict__ bff2,
                     const float* __restrict__ Wta,  const float* __restrict__ bta,
                     const float* __restrict__ Wtb,  const float* __restrict__ btb,
                     float* __restrict__ out)
{
    // b64-packed transposed buffers (old dword-row d -> [d>>1][lane][d&1])
    __shared__ __align__(16) unsigned hbuf[2][64][2];  // h pairs
    __shared__ __align__(16) unsigned abuf[4][64][2];  // acts; A2 frag kt = [2kt],[2kt+1]
    __shared__ __align__(16) unsigned xbuf[4][18][2];  // packed x; stride-18 pad (banks)

    const int tid  = threadIdx.x;
    const int w    = tid >> 6;          // wave id 0..3
    const int lane = tid & 63;
    const int ln   = lane & 15;         // MFMA m/n (pixel for B/C)
    const int lq   = lane >> 4;         // MFMA quad

    const int gpix = blockIdx.x * NPIX;
    const int b    = gpix >> 12;
    const int pinb = gpix & 4095;
    const int mt   = w;                 // phase-1 m-tile

    // ---- Wh A-frags (recurrent K=32): k=lq*8+j -> unit, Wb col 16+k -------
    bf16x8 Whhi, Whlo;
    {
        float v[8];
        #pragma unroll
        for (int j = 0; j < 8; ++j)
            v[j] = Wb[(mt * 16 + ln) * CZ + CIN + lq * 8 + j];
        split8(v, Whhi, Whlo);
    }
    // ---- Wx A-frags (x K=16 in a K=32 tile): k -> ch (lq<2), else 0 -------
    bf16x8 Wxhi, Wxlo;
    {
        float v[8];
        #pragma unroll
        for (int j = 0; j < 8; ++j)
            v[j] = (lq < 2) ? Wb[(mt * 16 + ln) * CZ + lq * 8 + j] : 0.0f;
        split8(v, Wxhi, Wxlo);
    }
    // backbone bias as persistent C-in vector; persistent zero C-in
    float4v BBv, Z4;
    #pragma unroll
    for (int r = 0; r < 4; ++r) { BBv[r] = bb[mt * 16 + lq * 4 + r]; Z4[r] = 0.0f; }

    // ---- phase-2 A frags: head tiles 2w+i2, HI ONLY -----------------------
    //      row ln -> unit (ln>>2)*8+tile, head ln&3;
    //      col n = 32kt + (j>>2)*16 + lq*4 + (j&3)
    const int head = ln & 3;
    const float* Whp = (head == 0) ? Wff1 : (head == 1) ? Wff2 : (head == 2) ? Wta : Wtb;
    const int urow = (ln >> 2) * 8;
    bf16x8 Ah[2][2];
    #pragma unroll
    for (int i2 = 0; i2 < 2; ++i2) {
        #pragma unroll
        for (int kt = 0; kt < 2; ++kt) {
            float v[8];
            #pragma unroll
            for (int j = 0; j < 8; ++j) {
                int n = 32 * kt + (j >> 2) * 16 + lq * 4 + (j & 3);
                v[j] = Whp[(urow + 2 * w + i2) * BACKBONE + n];
            }
            Ah[i2][kt] = pack8hi(v);
        }
    }
    // gate-side units of THIS lane: lq*8 + 2w + i2; bias as C-in vectors
    const int ub = lq * 8;
    float4v HBv[2];
    #pragma unroll
    for (int i2 = 0; i2 < 2; ++i2) {
        int u2 = ub + 2 * w + i2;
        HBv[i2][0] = bff1[u2]; HBv[i2][1] = bff2[u2];
        HBv[i2][2] = bta[u2];  HBv[i2][3] = btb[u2];
    }

    // ---- x producer params: row r = 2w+lq (lanes lq<2), ch (2r, 2r+1) -----
    const int  xr  = 2 * w + (lq & 1);
    const bool xpr = (lq < 2);
    const unsigned xi0 = ((unsigned)(b * CIN + 2 * xr) * TSTEPS) * HW
                         + (unsigned)(pinb + ln);
    const unsigned xi1 = xi0 + (unsigned)(TSTEPS * HW);

    // consumer b64 rows: r2base, r2base+1 (lq>=2 broadcast-dup lq-2)
    const int r2base = (lq & 1) * 2;

    unsigned oo[2];
    #pragma unroll
    for (int i2 = 0; i2 < 2; ++i2)
        oo[i2] = ((unsigned)(b * UNITS + ub + 2 * w + i2) * TSTEPS) * HW
                 + (unsigned)(pinb + ln);

    // X frag from 2 b64 xbuf reads (old rows r2base*2 .. r2base*2+3)
    auto xread = [&]() {
        uint2v x01 = *(const uint2v*)&xbuf[r2base][ln][0];
        uint2v x23 = *(const uint2v*)&xbuf[r2base + 1][ln][0];
        uint4v u = {x01[0], x01[1], x23[0], x23[1]};
        return u;
    };

    // ---- prologue ----------------------------------------------------------
    ((unsigned*)hbuf)[tid] = 0u;                    // h0 = 0 (256 dwords)
    if (xpr) {
        float a0 = x[xi0], a1 = x[xi1];             // x_0
        xbuf[xr >> 1][ln][xr & 1] = cvt_pk_bf16(a0, a1);
    }
    __syncthreads();
    float4v xzA, xzB;
    {
        uint4v u = xread();
        bf16x8 X0 = __builtin_bit_cast(bf16x8, u);
        float4v a = mfma16(Wxhi, X0, BBv);
        a = mfma16(Wxlo, X0, a);
        xzA = a;                                    // xz_0
    }
    __syncthreads();                                // xbuf reads done
    float pc0 = 0.f, pc1 = 0.f, pn0 = 0.f, pn1 = 0.f;
    if (xpr) {
        float a0 = x[xi0 + HW], a1 = x[xi1 + HW];   // x_1
        xbuf[xr >> 1][ln][xr & 1] = cvt_pk_bf16(a0, a1);
        pc0 = x[xi0 + 2u * HW]; pc1 = x[xi1 + 2u * HW];   // x_2 (in flight)
    }
    __syncthreads();                                // xbuf = x_1; loop invariant
    unsigned toff = 0;

    __builtin_amdgcn_s_setprio(1);                  // chain priority default

    // invariant at step t entry: xbuf = x_{t+1}; pc = x_{t+2}; xzc = xz_t.
    auto step = [&](int t, float4v xzc, float4v& xzn,
                    float& c0, float& c1, float& n0, float& n1) {
        // issue loads of x_{t+3} (consumed at publish point of step t+1)
        const unsigned tl = (unsigned)((t + 3 < TSTEPS) ? t + 3 : TSTEPS - 1);
        if (xpr) { n0 = x[xi0 + tl * HW]; n1 = x[xi1 + tl * HW]; }

        // read x_{t+1} frag (before BAR A; publish happens after BAR A)
        uint4v xfu = xread();

        // ---- phase 1 (prio 1): Z = hbuf b64x2; parallel hi/lo; lecun ----
        uint2v hA = *(const uint2v*)&hbuf[0][lane][0];
        uint2v hB = *(const uint2v*)&hbuf[1][lane][0];
        uint4v zv = {hA[0], hA[1], hB[0], hB[1]};
        bf16x8 Z = __builtin_bit_cast(bf16x8, zv);
        float4v ah = mfma16(Whhi, Z, xzc);
        float4v al = mfma16(Whlo, Z, Z4);
        float4v a  = ah + al;
        float g0 = lecun_tanh_f(a[0]);
        float g1 = lecun_tanh_f(a[1]);
        float g2 = lecun_tanh_f(a[2]);
        float g3 = lecun_tanh_f(a[3]);
        uint2v ad = {cvt_pk_bf16(g0, g1), cvt_pk_bf16(g2, g3)};
        *(uint2v*)&abuf[mt][lane][0] = ad;          // ds_write_b64
        BAR_LDS();                      // barrier A: acts published, x reads done

        // ---- filler (prio 0): publish x_{t+2}; compute xz_{t+1} ----
        __builtin_amdgcn_s_setprio(0);
        if (xpr) xbuf[xr >> 1][ln][xr & 1] = cvt_pk_bf16(c0, c1);
        {
            bf16x8 X = __builtin_bit_cast(bf16x8, xfu);
            float4v q = mfma16(Wxhi, X, BBv);
            q = mfma16(Wxlo, X, q);
            xzn = q;
        }
        __builtin_amdgcn_s_setprio(1);

        // ---- assemble A2: 4 b64 reads (frag kt = [2kt],[2kt+1]) ----
        uint2v a0 = *(const uint2v*)&abuf[0][lane][0];
        uint2v a1 = *(const uint2v*)&abuf[1][lane][0];
        uint2v a2 = *(const uint2v*)&abuf[2][lane][0];
        uint2v a3 = *(const uint2v*)&abuf[3][lane][0];
        uint4v w0 = {a0[0], a0[1], a1[0], a1[1]};
        uint4v w1 = {a2[0], a2[1], a3[0], a3[1]};
        bf16x8 A20 = __builtin_bit_cast(bf16x8, w0);
        bf16x8 A21 = __builtin_bit_cast(bf16x8, w1);

        // ---- phase 2: 2 head tiles, parallel kt chains, gate, store ----
        float hn[2];
        #pragma unroll
        for (int i2 = 0; i2 < 2; ++i2) {
            float4v ch = mfma16(Ah[i2][0], A20, HBv[i2]);
            float4v cl = mfma16(Ah[i2][1], A21, Z4);
            float4v c  = ch + cl;
            float f1g = tanh_f(c[0]);
            float f2g = tanh_f(c[1]);
            float ti  = sigmoid_f(c[2] + c[3]);
            float h   = fmaf(ti, f2g - f1g, f1g);
            out[oo[i2] + toff] = h;     // async store; never drained in loop
            hn[i2] = h;
        }
        hbuf[w >> 1][lane][w & 1] = cvt_pk_bf16(hn[0], hn[1]);
        BAR_LDS();                      // barrier B: h + x_{t+2} ready
        toff += (unsigned)HW;
    };

    #pragma unroll 1
    for (int t = 0; t < TSTEPS; t += 2) {
        step(t,     xzA, xzB, pc0, pc1, pn0, pn1);   // ping
        step(t + 1, xzB, xzA, pn0, pn1, pc0, pc1);   // pong (static, rule #20)
    }
}

extern "C" void kernel_launch(void* const* d_in, const int* in_sizes, int n_in,
                              void* d_out, int out_size, void* d_ws, size_t ws_size,
                              hipStream_t stream) {
    dim3 grid(4 * HW / NPIX);   // 1024 blocks x 4 waves -> 4 blocks/CU
    cfc_mfma_kernel<<<grid, NTHREADS, 0, stream>>>(
        (const float*)d_in[0], (const float*)d_in[1], (const float*)d_in[2],
        (const float*)d_in[3], (const float*)d_in[4], (const float*)d_in[5],
        (const float*)d_in[6], (const float*)d_in[7], (const float*)d_in[8],
        (const float*)d_in[9], (const float*)d_in[10],
        (float*)d_out);
}

// Round 12
// 145.502 us; speedup vs baseline: 1.0049x; 1.0049x over previous
//
#include <hip/hip_runtime.h>
#include <hip/hip_bf16.h>

// CfC / liquid-RNN scan on MFMA, R19: 2-WAVE teams (team-size probe).
// R17 post-mortem: LDS-op diet + conflict fix = flat -> issue-count no
// longer binding. Residual wall model: chain (~900cy) x convoy(~2) from the
// 4-wave lockstep team (slowest-of-4 at each barrier + post-release burst
// contention). R19 isolates team size: wave w in {0,1} owns m-tiles
// {2w,2w+1} (phase1) and head tiles {4w..4w+3} (phase2); barriers sync 2
// waves instead of 4. Per-SIMD issued work unchanged (2 waves x 2x work);
// occupancy 2 waves/SIMD (8/CU). ALL math bitwise = R17 (same operands,
// order, quantization) -> absmax must be exactly 0.00994873 (tripwire).
// If this regresses, covering>convoy and the plateau is structural.

#define CIN      16
#define UNITS    32
#define BACKBONE 64
#define CZ       48
#define TSTEPS   32
#define HW       4096
#define NPIX     16
#define NTHREADS 128

typedef __attribute__((ext_vector_type(8))) short  short8;
typedef __attribute__((ext_vector_type(8))) __bf16 bf16x8;
typedef __attribute__((ext_vector_type(4))) float  float4v;
typedef __attribute__((ext_vector_type(4))) unsigned int uint4v;
typedef __attribute__((ext_vector_type(2))) unsigned int uint2v;

// LDS-only barrier: drain LDS pipe, sync waves; vmem stays in flight.
#define BAR_LDS() asm volatile("s_waitcnt lgkmcnt(0)\n\ts_barrier" ::: "memory")

__device__ __forceinline__ unsigned short bf16_rne(float f) {
    unsigned u = __float_as_uint(f);
    return (unsigned short)((u + 0x7FFFu + ((u >> 16) & 1u)) >> 16);
}
__device__ __forceinline__ float bf16_tof(unsigned short h) {
    return __uint_as_float(((unsigned)h) << 16);
}
// packed f32x2 -> bf16x2 (RNE), single VALU op
__device__ __forceinline__ unsigned cvt_pk_bf16(float lo, float hi) {
    unsigned r;
    asm("v_cvt_pk_bf16_f32 %0, %1, %2" : "=v"(r) : "v"(lo), "v"(hi));
    return r;
}

#if __has_builtin(__builtin_amdgcn_exp2f)
#define EXP2F(x) __builtin_amdgcn_exp2f(x)
#else
#define EXP2F(x) __expf(0.69314718056f * (x))
#endif
#if __has_builtin(__builtin_amdgcn_rcpf)
#define RCPF(x) __builtin_amdgcn_rcpf(x)
#else
#define RCPF(x) __fdividef(1.0f, (x))
#endif

// 1.7159*tanh(0.666*v) = 1.7159 - 3.4318/(2^(1.332*log2e*v)+1)
__device__ __forceinline__ float lecun_tanh_f(float v) {
    float e = EXP2F(1.92166925f * v);
    return fmaf(-3.4318f, RCPF(e + 1.0f), 1.7159f);
}
__device__ __forceinline__ float tanh_f(float v) {
    float e = EXP2F(2.88539008f * v);
    return fmaf(-2.0f, RCPF(e + 1.0f), 1.0f);
}
__device__ __forceinline__ float sigmoid_f(float v) {
    float e = EXP2F(-1.44269504f * v);
    return RCPF(1.0f + e);
}
__device__ __forceinline__ float4v mfma16(bf16x8 a, bf16x8 b, float4v c) {
    return __builtin_amdgcn_mfma_f32_16x16x32_bf16(a, b, c, 0, 0, 0);
}
__device__ __forceinline__ void split8(const float* v, bf16x8& hi, bf16x8& lo) {
    short8 sh, sl;
    #pragma unroll
    for (int j = 0; j < 8; ++j) {
        unsigned short h = bf16_rne(v[j]);
        sh[j] = (short)h;
        sl[j] = (short)bf16_rne(v[j] - bf16_tof(h));
    }
    hi = __builtin_bit_cast(bf16x8, sh);
    lo = __builtin_bit_cast(bf16x8, sl);
}
__device__ __forceinline__ bf16x8 pack8hi(const float* v) {
    short8 sh;
    #pragma unroll
    for (int j = 0; j < 8; ++j) sh[j] = (short)bf16_rne(v[j]);
    return __builtin_bit_cast(bf16x8, sh);
}

__global__ __launch_bounds__(NTHREADS, 2)
void cfc_mfma_kernel(const float* __restrict__ x,   const float* __restrict__ Wb,
                     const float* __restrict__ bb,
                     const float* __restrict__ Wff1, const float* __restrict__ bff1,
                     const float* __restrict__ Wff2, const float* __restrict__ bff2,
                     const float* __restrict__ Wta,  const float* __restrict__ bta,
                     const float* __restrict__ Wtb,  const float* __restrict__ btb,
                     float* __restrict__ out)
{
    // b64-packed transposed buffers (layouts identical to R17)
    __shared__ __align__(16) unsigned hbuf[2][64][2];  // h pairs
    __shared__ __align__(16) unsigned abuf[4][64][2];  // acts; A2 frag kt = [2kt],[2kt+1]
    __shared__ __align__(16) unsigned xbuf[4][18][2];  // packed x; stride-18 pad

    const int tid  = threadIdx.x;
    const int w    = tid >> 6;          // wave id 0..1
    const int lane = tid & 63;
    const int ln   = lane & 15;         // MFMA m/n (pixel for B/C)
    const int lq   = lane >> 4;         // MFMA quad

    const int gpix = blockIdx.x * NPIX;
    const int b    = gpix >> 12;
    const int pinb = gpix & 4095;

    // ---- phase-1 A frags: m-tiles 2w, 2w+1 (hi+lo) ------------------------
    bf16x8 Whhi[2], Whlo[2], Wxhi[2], Wxlo[2];
    float4v BBv[2], Z4;
    #pragma unroll
    for (int r = 0; r < 4; ++r) Z4[r] = 0.0f;
    #pragma unroll
    for (int i = 0; i < 2; ++i) {
        const int mt = 2 * w + i;
        float v[8];
        #pragma unroll
        for (int j = 0; j < 8; ++j)
            v[j] = Wb[(mt * 16 + ln) * CZ + CIN + lq * 8 + j];
        split8(v, Whhi[i], Whlo[i]);
        #pragma unroll
        for (int j = 0; j < 8; ++j)
            v[j] = (lq < 2) ? Wb[(mt * 16 + ln) * CZ + lq * 8 + j] : 0.0f;
        split8(v, Wxhi[i], Wxlo[i]);
        #pragma unroll
        for (int r = 0; r < 4; ++r) BBv[i][r] = bb[mt * 16 + lq * 4 + r];
    }

    // ---- phase-2 A frags: head tiles 4w+i2 (i2=0..3), HI ONLY -------------
    const int head = ln & 3;
    const float* Whp = (head == 0) ? Wff1 : (head == 1) ? Wff2 : (head == 2) ? Wta : Wtb;
    const int urow = (ln >> 2) * 8;
    bf16x8 Ah[4][2];
    float4v HBv[4];
    const int ub = lq * 8;
    #pragma unroll
    for (int i2 = 0; i2 < 4; ++i2) {
        const int ti = 4 * w + i2;
        #pragma unroll
        for (int kt = 0; kt < 2; ++kt) {
            float v[8];
            #pragma unroll
            for (int j = 0; j < 8; ++j) {
                int n = 32 * kt + (j >> 2) * 16 + lq * 4 + (j & 3);
                v[j] = Whp[(urow + ti) * BACKBONE + n];
            }
            Ah[i2][kt] = pack8hi(v);
        }
        int u2 = ub + ti;
        HBv[i2][0] = bff1[u2]; HBv[i2][1] = bff2[u2];
        HBv[i2][2] = bta[u2];  HBv[i2][3] = btb[u2];
    }

    // ---- x producer: lanes lq<2 own ch-pair rows r0=4w+2(lq&1), r0+1 ------
    const bool xpr = (lq < 2);
    const int  xrow2 = 2 * w + (lq & 1);            // xbuf b64 row owned
    const int  chb   = 8 * w + 4 * (lq & 1);        // first channel
    unsigned xi[4];
    #pragma unroll
    for (int k = 0; k < 4; ++k)
        xi[k] = ((unsigned)(b * CIN + chb + k) * TSTEPS) * HW + (unsigned)(pinb + ln);

    // consumer b64 rows: r2base, r2base+1
    const int r2base = (lq & 1) * 2;

    unsigned oo[4];
    #pragma unroll
    for (int i2 = 0; i2 < 4; ++i2)
        oo[i2] = ((unsigned)(b * UNITS + ub + 4 * w + i2) * TSTEPS) * HW
                 + (unsigned)(pinb + ln);

    auto xread = [&]() {
        uint2v x01 = *(const uint2v*)&xbuf[r2base][ln][0];
        uint2v x23 = *(const uint2v*)&xbuf[r2base + 1][ln][0];
        uint4v u = {x01[0], x01[1], x23[0], x23[1]};
        return u;
    };
    auto xstage = [&](const float (&v)[4]) {        // pack+publish own b64 row
        uint2v d = {cvt_pk_bf16(v[0], v[1]), cvt_pk_bf16(v[2], v[3])};
        *(uint2v*)&xbuf[xrow2][ln][0] = d;
    };

    // ---- prologue ----------------------------------------------------------
    ((unsigned*)hbuf)[tid] = 0u;                    // h0 = 0 (256 dwords)
    ((unsigned*)hbuf)[tid + 128] = 0u;
    float pc[4] = {0, 0, 0, 0}, pn[4] = {0, 0, 0, 0};
    if (xpr) {
        float v0[4];
        #pragma unroll
        for (int k = 0; k < 4; ++k) v0[k] = x[xi[k]];
        xstage(v0);
    }
    __syncthreads();
    float4v xzA[2], xzB[2];
    {
        uint4v u = xread();
        bf16x8 X0 = __builtin_bit_cast(bf16x8, u);
        #pragma unroll
        for (int i = 0; i < 2; ++i) {
            float4v a = mfma16(Wxhi[i], X0, BBv[i]);
            a = mfma16(Wxlo[i], X0, a);
            xzA[i] = a;                             // xz_0
        }
    }
    __syncthreads();                                // xbuf reads done
    if (xpr) {
        float v1[4];
        #pragma unroll
        for (int k = 0; k < 4; ++k) v1[k] = x[xi[k] + HW];
        xstage(v1);
        #pragma unroll
        for (int k = 0; k < 4; ++k) pc[k] = x[xi[k] + 2u * HW];  // x_2 in flight
    }
    __syncthreads();                                // xbuf = x_1; loop invariant
    unsigned toff = 0;

    __builtin_amdgcn_s_setprio(1);

    // invariant at step t entry: xbuf = x_{t+1}; pc = x_{t+2}; xzc = xz_t.
    auto step = [&](int t, float4v (&xzc)[2], float4v (&xzn)[2],
                    float (&c)[4], float (&n)[4]) {
        const unsigned tl = (unsigned)((t + 3 < TSTEPS) ? t + 3 : TSTEPS - 1);
        if (xpr) {
            #pragma unroll
            for (int k = 0; k < 4; ++k) n[k] = x[xi[k] + tl * HW];
        }
        uint4v xfu = xread();                       // x_{t+1} (pre-BAR A)

        // ---- phase 1: Z = hbuf; 2 m-tiles, parallel hi/lo; lecun; publish -
        uint2v hA = *(const uint2v*)&hbuf[0][lane][0];
        uint2v hB = *(const uint2v*)&hbuf[1][lane][0];
        uint4v zv = {hA[0], hA[1], hB[0], hB[1]};
        bf16x8 Z = __builtin_bit_cast(bf16x8, zv);
        #pragma unroll
        for (int i = 0; i < 2; ++i) {
            float4v ah = mfma16(Whhi[i], Z, xzc[i]);
            float4v al = mfma16(Whlo[i], Z, Z4);
            float4v a  = ah + al;
            float g0 = lecun_tanh_f(a[0]);
            float g1 = lecun_tanh_f(a[1]);
            float g2 = lecun_tanh_f(a[2]);
            float g3 = lecun_tanh_f(a[3]);
            uint2v ad = {cvt_pk_bf16(g0, g1), cvt_pk_bf16(g2, g3)};
            *(uint2v*)&abuf[2 * w + i][lane][0] = ad;
        }
        BAR_LDS();                      // barrier A: acts published, x reads done

        // ---- filler (prio 0): publish x_{t+2}; compute xz_{t+1} ----
        __builtin_amdgcn_s_setprio(0);
        if (xpr) xstage(c);
        {
            bf16x8 X = __builtin_bit_cast(bf16x8, xfu);
            #pragma unroll
            for (int i = 0; i < 2; ++i) {
                float4v q = mfma16(Wxhi[i], X, BBv[i]);
                q = mfma16(Wxlo[i], X, q);
                xzn[i] = q;
            }
        }
        __builtin_amdgcn_s_setprio(1);

        // ---- assemble A2: 4 b64 reads (frag kt = [2kt],[2kt+1]) ----
        uint2v a0 = *(const uint2v*)&abuf[0][lane][0];
        uint2v a1 = *(const uint2v*)&abuf[1][lane][0];
        uint2v a2 = *(const uint2v*)&abuf[2][lane][0];
        uint2v a3 = *(const uint2v*)&abuf[3][lane][0];
        uint4v w0 = {a0[0], a0[1], a1[0], a1[1]};
        uint4v w1 = {a2[0], a2[1], a3[0], a3[1]};
        bf16x8 A20 = __builtin_bit_cast(bf16x8, w0);
        bf16x8 A21 = __builtin_bit_cast(bf16x8, w1);

        // ---- phase 2: 4 head tiles, parallel kt chains, gate, store ----
        float hn[4];
        #pragma unroll
        for (int i2 = 0; i2 < 4; ++i2) {
            float4v ch = mfma16(Ah[i2][0], A20, HBv[i2]);
            float4v cl = mfma16(Ah[i2][1], A21, Z4);
            float4v cc = ch + cl;
            float f1g = tanh_f(cc[0]);
            float f2g = tanh_f(cc[1]);
            float ti  = sigmoid_f(cc[2] + cc[3]);
            float h   = fmaf(ti, f2g - f1g, f1g);
            out[oo[i2] + toff] = h;     // async store; never drained in loop
            hn[i2] = h;
        }
        uint2v hd = {cvt_pk_bf16(hn[0], hn[1]), cvt_pk_bf16(hn[2], hn[3])};
        *(uint2v*)&hbuf[w][lane][0] = hd;
        BAR_LDS();                      // barrier B: h + x_{t+2} ready
        toff += (unsigned)HW;
    };

    #pragma unroll 1
    for (int t = 0; t < TSTEPS; t += 2) {
        step(t,     xzA, xzB, pc, pn);   // ping
        step(t + 1, xzB, xzA, pn, pc);   // pong (static indexing, rule #20)
    }
}

extern "C" void kernel_launch(void* const* d_in, const int* in_sizes, int n_in,
                              void* d_out, int out_size, void* d_ws, size_t ws_size,
                              hipStream_t stream) {
    dim3 grid(4 * HW / NPIX);   // 1024 blocks x 2 waves -> 2 waves/SIMD
    cfc_mfma_kernel<<<grid, NTHREADS, 0, stream>>>(
        (const float*)d_in[0], (const float*)d_in[1], (const float*)d_in[2],
        (const float*)d_in[3], (const float*)d_in[4], (const float*)d_in[5],
        (const float*)d_in[6], (const float*)d_in[7], (const float*)d_in[8],
        (const float*)d_in[9], (const float*)d_in[10],
        (float*)d_out);
}